// Round 9
// baseline (277.480 us; speedup 1.0000x reference)
//
#include <hip/hip_runtime.h>
#include <math.h>

// ============================================================================
// WaveletBasis as bf16 MFMA GEMM: M=32768(B), N=64(O), K=1024*9.
// Aligned run layout: 128 runs, run R = features [8R,8R+8); run = 9 qslots
// (qslot f<8 = basis octet of feature 8R+f, qslot 8 = x-octet).
// Chunk c = runs [4c,4c+4) = 9 K32-steps.
//
// ROUND 10: round 9 (zero-barrier, reg-A, scattered x) PASSED but 130us --
// refutes the "barriers are the floor" theory (removed all barriers, 60%
// slower; MfmaUtil 11.7 = static count over a bigger wall, all pipes idle).
// Diagnosis: row-scattered x reads (32 lines/instr @ 4KB stride) sit on each
// wave's per-chunk serial chain with no decoupling. Fix: keep the VERIFIED
// reg-A math byte-identical; re-route ONLY x through a double-buffered LDS
// tile XT[2][64][33] f32 (16.9KB):
//  - coalesced stage: 1 float4/thread/chunk (8 thr/row = full 128B lines),
//    issued one chunk ahead; 1 barrier/chunk (R5's proven discipline).
//  - consumers do 4-12 ds_read_b32; stride 33 -> bank=(row+col)%32,
//    conflict-free. LDS/chunk: 8.4KB write + ~10KB read (R5: 36+72KB, A-tile
//    now lives in registers via per-lane gen_basis).
//  - B loads, tanh, gen_basis, x-duty u-split, P[4] epilogue: unchanged.
// ============================================================================

typedef __attribute__((ext_vector_type(8))) short short8;
typedef __attribute__((ext_vector_type(4))) float f32x4;
typedef __attribute__((ext_vector_type(16))) float f32x16;

__device__ __forceinline__ unsigned int f2bf(float f) {
  unsigned int u = __float_as_uint(f);
  u += 0x7FFFu + ((u >> 16) & 1u);   // RNE; finite inputs
  return u >> 16;
}

// 4 dwords = 8 bf16 basis values (n=0..7) as a function of bucket j.
__device__ __forceinline__ void gen_basis(int j, unsigned int* d) {
  d[0] = (j < 4) ? 0x3F803F80u : 0xBF803F80u;                  // [phi=1, psi0=+-1]
  unsigned int sq1 = (j & 2) ? 0xBFB5u : 0x3FB5u;              // +-sqrt2
  d[1] = (j & 4) ? (sq1 << 16) : sq1;                          // one-hot k1=j>>2
  unsigned long long sd2 = (j & 1) ? 0xC000ull : 0x4000ull;    // +-2
  unsigned long long d23 = sd2 << ((j & 6) << 3);              // << 16*(j>>1)
  d[2] = (unsigned int)d23;
  d[3] = (unsigned int)(d23 >> 32);
}

#define BARRIER() __asm__ volatile("s_waitcnt lgkmcnt(0)\n\ts_barrier" ::: "memory")

// ---------------------------------------------------------------------------
// K1: W into 32x32x16 B-fragment order under the aligned run layout.
// Fragment (c,s,u,nq) at Bsw[((c*9+s)*4 + 2u + nq)*64 + l]: lane l holds
// col o = 32nq+(l&31), k = qslot s of run R = 4c+2u+(l>>5). Short jj:
// s<8 -> (f=8R+s, n=jj); s==8 -> (f=8R+jj, n=8 i.e. base_weight).
// (Unchanged; verified rounds 6-9.)
// ---------------------------------------------------------------------------
__global__ __launch_bounds__(256) void build_w(const float* __restrict__ coeffs,
                                               const float* __restrict__ bw,
                                               uint4* __restrict__ Wsw) {
  const int l = threadIdx.x & 63;
  const int t = threadIdx.x >> 6;   // t = 2u+nq, 0..3
  const int g = blockIdx.x;         // 0..287
  const int c = g / 9, j = g - c * 9;
  const int u = t >> 1, nq = t & 1;
  const int R = c * 4 + 2 * u + (l >> 5);
  const int o = nq * 32 + (l & 31);
  unsigned int dwv[4];
#pragma unroll
  for (int jj = 0; jj < 8; ++jj) {
    int f, n;
    if (j < 8) { f = 8 * R + j;  n = jj; }
    else       { f = 8 * R + jj; n = 8;  }
    float v = (n < 8) ? coeffs[(f * 64 + o) * 8 + n] : bw[f * 64 + o];
    unsigned int hh = f2bf(v);
    if (jj & 1) dwv[jj >> 1] |= hh << 16; else dwv[jj >> 1] = hh;
  }
  uint4 qq; qq.x = dwv[0]; qq.y = dwv[1]; qq.z = dwv[2]; qq.w = dwv[3];
  Wsw[(g * 4 + t) * 64 + l] = qq;
}

#define MFMA32(A, B, C) __builtin_amdgcn_mfma_f32_32x32x16_bf16( \
    __builtin_bit_cast(short8, (A)), __builtin_bit_cast(short8, (B)), (C), 0, 0, 0)

// ---------------------------------------------------------------------------
// K2: 512 blocks x 512 thr. Block = 64 rows x 64 cols.
// Wave w: ks = w>>1 (basis slots {2ks,2ks+1}), mh = w&1 (rows 32mh..+32).
// Lane l: row = 32mh + (l&31); hi = l>>5 selects run parity (2u+hi).
// x-slot (qslot 8): waves ks in {0,1} handle u=ks, both nq fragments.
// A-fragments built in registers from the LDS x-tile; 1 barrier/chunk.
// LDS: 64KB union -- XT[2][64][33] f32 (16.9KB) in-loop; P[4][64][64]
// ks-partials at epilogue.
// ---------------------------------------------------------------------------
__global__ __launch_bounds__(512, 4) void wavelet_gemm(const float* __restrict__ x,
                                                       const uint4* __restrict__ Bsw,
                                                       float* __restrict__ out,
                                                       int out_size) {
  __shared__ float LDSu[4 * 4096];   // 64 KB
  float* const XT0 = LDSu;           // [64][33] chunk x-tile, buffer 0
  float* const XT1 = LDSu + 64 * 33; // buffer 1
  const int tid = threadIdx.x;
  const int l = tid & 63;
  const int w = tid >> 6;            // wave 0..7
  const int ks = w >> 1;             // basis slot pair {2ks, 2ks+1}
  const int mh = w & 1;              // row half
  const int hi = l >> 5;
  const int l31 = l & 31;
  const long rowbase = (long)blockIdx.x * 64;
  const int sA = 2 * ks;             // first basis slot
  const int xduty = (ks < 2);        // x-slot owner: u = ks
  const int xrun = 2 * ks + hi;      // x-octet run_local (only used if xduty)

  // stage role (all 512 threads): row = tid>>3, cols (tid&7)*4 .. +4
  const int srow = tid >> 3;
  const int scol = (tid & 7) * 4;
  const float* sp = x + (rowbase + srow) * 1024 + scol;
  float* const sd0 = XT0 + srow * 33 + scol;
  float* const sd1 = XT1 + srow * 33 + scol;

  // consumer LDS bases (row = l31 within the mh half -> tile row 32mh+l31)
  const float* const xrow_lds0 = XT0 + (32 * mh + l31) * 33;
  const float* const xrow_lds1 = XT1 + (32 * mh + l31) * 33;

  f32x16 acc0 = {};                  // cols 0..31
  f32x16 acc1 = {};                  // cols 32..63

  // ---- prologue: stage chunk 0 into XT0 ----------------------------------
  {
    float4 g0 = *(const float4*)(sp);
    sd0[0] = g0.x; sd0[1] = g0.y; sd0[2] = g0.z; sd0[3] = g0.w;
  }
  BARRIER();

#pragma unroll 1
  for (int c = 0; c < 32; ++c) {
    // ---- B fragments for this chunk's two basis slots (L2-hot) -----------
    const uint4* wp = Bsw + ((size_t)(c * 9 + sA) * 4) * 64 + l;
    uint4 BA0 = wp[0],   BA1 = wp[64],  BA2 = wp[128], BA3 = wp[192];
    uint4 BB0 = wp[256], BB1 = wp[320], BB2 = wp[384], BB3 = wp[448];
    // ---- global x for chunk c+1 (coalesced; hidden under this chunk) -----
    float4 gn;
    if (c + 1 < 32) gn = *(const float4*)(sp + 32 * (c + 1));
    // ---- x for the 4 basis features from the LDS tile ---------------------
    const float* Xc = (c & 1) ? xrow_lds1 : xrow_lds0;
    float xv[4];
    xv[0] = Xc[8 * hi + sA];       xv[1] = Xc[8 * hi + sA + 1];
    xv[2] = Xc[8 * (2 + hi) + sA]; xv[3] = Xc[8 * (2 + hi) + sA + 1];

    // ---- tanh/bucket (verified numerics) ---------------------------------
    float t8v[4];
    unsigned int bad = 0;
#pragma unroll
    for (int ff = 0; ff < 4; ++ff) {
      float e = __expf(2.0f * xv[ff]);               // t8 = 8 - 8/(e+1)
      float r = __builtin_amdgcn_rcpf(e + 1.0f);
      float t8 = __builtin_fmaf(-8.0f, r, 8.0f);
      float rn = rintf(t8);
      if (fabsf(t8 - rn) < 3e-5f) bad |= 1u << ff;
      t8v[ff] = t8;
    }
    if (__builtin_expect(bad != 0, 0)) {
#pragma unroll
      for (int ff = 0; ff < 4; ++ff)
        if (bad & (1u << ff)) {
          float tf = (float)tanh((double)xv[ff]);    // ref-fidelity fallback
          t8v[ff] = ((tf + 1.0f) * 0.5f) * 8.0f;     // exact ref f32 pipeline
        }
    }
    // ---- A-fragments in registers: gen_basis output = lane's k-octet -----
    uint4 A[4];
#pragma unroll
    for (int ff = 0; ff < 4; ++ff) {
      int j = (int)t8v[ff]; j = j > 7 ? 7 : j;       // t8 in [0,8]
      unsigned int d[4];
      gen_basis(j, d);
      A[ff].x = d[0]; A[ff].y = d[1]; A[ff].z = d[2]; A[ff].w = d[3];
    }
    // slot sA:   u0 = A[0] (run hi),  u1 = A[2] (run 2+hi)
    acc0 = MFMA32(A[0], BA0, acc0);
    acc1 = MFMA32(A[0], BA1, acc1);
    acc0 = MFMA32(A[2], BA2, acc0);
    acc1 = MFMA32(A[2], BA3, acc1);
    // slot sA+1: u0 = A[1],           u1 = A[3]
    acc0 = MFMA32(A[1], BB0, acc0);
    acc1 = MFMA32(A[1], BB1, acc1);
    acc0 = MFMA32(A[3], BB2, acc0);
    acc1 = MFMA32(A[3], BB3, acc1);
    // ---- x-slot: wave ks in {0,1} owns u=ks, both nq (verified r9) -------
    if (xduty) {
      const uint4* wx = Bsw + ((size_t)(c * 9 + 8) * 4) * 64 + l;
      uint4 BXa = wx[(2 * ks) * 64];         // t = 2u+0
      uint4 BXb = wx[(2 * ks + 1) * 64];     // t = 2u+1
      float xo[8];
#pragma unroll
      for (int i = 0; i < 8; ++i) xo[i] = Xc[8 * xrun + i];
      uint4 xa;
      xa.x = f2bf(xo[0]) | (f2bf(xo[1]) << 16);
      xa.y = f2bf(xo[2]) | (f2bf(xo[3]) << 16);
      xa.z = f2bf(xo[4]) | (f2bf(xo[5]) << 16);
      xa.w = f2bf(xo[6]) | (f2bf(xo[7]) << 16);
      acc0 = MFMA32(xa, BXa, acc0);          // nq=0
      acc1 = MFMA32(xa, BXb, acc1);          // nq=1
    }
    // ---- stage chunk c+1 into the other buffer ---------------------------
    if (c + 1 < 32) {
      float* sd = ((c + 1) & 1) ? sd1 : sd0;
      sd[0] = gn.x; sd[1] = gn.y; sd[2] = gn.z; sd[3] = gn.w;
    }
    BARRIER();   // c+1 tile visible; reads of tile c drained
  }

  // ---- ks-partial store: P[ks][row][col]; 32x32 C/D layout (verified):
  // col = lane&31, row = (reg&3) + 8*(reg>>2) + 4*(lane>>5).
  float* P = LDSu;
  float* Pk = P + ks * 4096;
  const int rbase = 32 * mh + 4 * hi;
#pragma unroll
  for (int rg = 0; rg < 16; ++rg) {
    const int grow = (rg & 3) + 8 * (rg >> 2) + rbase;
    Pk[grow * 64 + l31]      = acc0[rg];
    Pk[grow * 64 + 32 + l31] = acc1[rg];
  }
  __syncthreads();

  // ---- reduce 4 ks-partials, flat & conflict-free; coalesced store ------
  float* og = out + (size_t)rowbase * 64;
  const int d = tid * 4;
  f32x4 v0 = *(const f32x4*)(P + d) + *(const f32x4*)(P + 4096 + d)
           + *(const f32x4*)(P + 8192 + d) + *(const f32x4*)(P + 12288 + d);
  f32x4 v1 = *(const f32x4*)(P + 2048 + d) + *(const f32x4*)(P + 6144 + d)
           + *(const f32x4*)(P + 10240 + d) + *(const f32x4*)(P + 14336 + d);
  *(f32x4*)(og + d) = v0;
  *(f32x4*)(og + 2048 + d) = v1;
  if (blockIdx.x == 0 && tid == 0) out[out_size - 1] = 0.0f;  // kl = 0
}

extern "C" void kernel_launch(void* const* d_in, const int* in_sizes, int n_in,
                              void* d_out, int out_size, void* d_ws, size_t ws_size,
                              hipStream_t stream) {
  const float* x      = (const float*)d_in[0];   // [32768,1024] f32
  const float* coeffs = (const float*)d_in[1];   // [1024,64,8] f32
  const float* bw     = (const float*)d_in[2];   // [1024,64] f32
  uint4* Wsw = (uint4*)d_ws;                     // 288*4*64*16 = 1.125 MiB
  float* out = (float*)d_out;

  build_w<<<288, 256, 0, stream>>>(coeffs, bw, Wsw);
  wavelet_gemm<<<512, 512, 0, stream>>>(x, (const uint4*)Wsw, out, out_size);
}

// Round 10
// 269.364 us; speedup vs baseline: 1.0301x; 1.0301x over previous
//
#include <hip/hip_runtime.h>
#include <math.h>

// ============================================================================
// WaveletBasis as bf16 MFMA GEMM: M=32768(B), N=64(O), K=1024*9.
// Aligned run layout: 128 runs, run R = features [8R,8R+8); run = 9 qslots
// (qslot f<8 = basis octet of feature 8R+f, qslot 8 = packed x-octet).
// Chunk c = runs [4c,4c+4) = 9 K16-pair steps. A tile (uint4):
//   idx = qslot*128 + run_local*32 + row   (32 rows/block).
//
// ROUND 11: R9/R10 (reg-A variants) proved the wall is NOT barriers, NOT x
// access pattern: VALU-time (~31us) and MFMA-time (~15us) are invariant
// across all structures; only stall moves. R5 (82us) wins because its MFMA
// (consumes LAST chunk's LDS tile) and builder VALU (produces NEXT) are
// independent within a chunk. Remaining R5 stall = barrier convergence of 2
// lockstep blocks/CU. This round: R5 dataflow, but 32-row x 256-thread
// blocks, LDS 36KB -> 4 blocks/CU at staggered phases fill each other's
// barrier waits. Wave = K-step quarter ks: steps {ks,ks+4[,8]}, all 64 cols;
// qslot-8 x-step is a normal A-fragment of ks=0 (verified R5 path).
// All ds accesses contiguous -> bank-clean without swizzle. setprio kept.
// Cost accepted: 1024 blocks double B L2-read rate (~half of L2 BW).
// ============================================================================

typedef __attribute__((ext_vector_type(8))) short short8;
typedef __attribute__((ext_vector_type(4))) float f32x4;
typedef __attribute__((ext_vector_type(16))) float f32x16;

__device__ __forceinline__ unsigned int f2bf(float f) {
  unsigned int u = __float_as_uint(f);
  u += 0x7FFFu + ((u >> 16) & 1u);   // RNE; finite inputs
  return u >> 16;
}

// 4 dwords = 8 bf16 basis values (n=0..7) as a function of bucket j.
__device__ __forceinline__ void gen_basis(int j, unsigned int* d) {
  d[0] = (j < 4) ? 0x3F803F80u : 0xBF803F80u;                  // [phi=1, psi0=+-1]
  unsigned int sq1 = (j & 2) ? 0xBFB5u : 0x3FB5u;              // +-sqrt2
  d[1] = (j & 4) ? (sq1 << 16) : sq1;                          // one-hot k1=j>>2
  unsigned long long sd2 = (j & 1) ? 0xC000ull : 0x4000ull;    // +-2
  unsigned long long d23 = sd2 << ((j & 6) << 3);              // << 16*(j>>1)
  d[2] = (unsigned int)d23;
  d[3] = (unsigned int)(d23 >> 32);
}

#define BARRIER() __asm__ volatile("s_waitcnt lgkmcnt(0)\n\ts_barrier" ::: "memory")

// ---------------------------------------------------------------------------
// Builder: half-run (features 4h..4h+4 of run) for one row -> 4 basis quads
// + packed x uint2 into the A tile (32-row strides). Verified numerics
// (fast tanh + rare ref-fidelity fixer).
// ---------------------------------------------------------------------------
__device__ __forceinline__ void build_half(const float4& xq, uint4* __restrict__ buf,
                                           int run, int row, int h) {
  float xv[4] = {xq.x, xq.y, xq.z, xq.w};
  float t8v[4];
  unsigned int bad = 0;
#pragma unroll
  for (int ff = 0; ff < 4; ++ff) {
    float e = __expf(2.0f * xv[ff]);                 // t8 = 8*e/(e+1) = 8 - 8/(e+1)
    float r = __builtin_amdgcn_rcpf(e + 1.0f);
    float t8 = __builtin_fmaf(-8.0f, r, 8.0f);
    float rn = rintf(t8);
    if (fabsf(t8 - rn) < 3e-5f) bad |= 1u << ff;
    t8v[ff] = t8;
  }
  if (__builtin_expect(bad != 0, 0)) {
#pragma unroll
    for (int ff = 0; ff < 4; ++ff)
      if (bad & (1u << ff)) {
        float tf = (float)tanh((double)xv[ff]);      // ref-fidelity fallback
        t8v[ff] = ((tf + 1.0f) * 0.5f) * 8.0f;       // exact ref f32 pipeline
      }
  }
  // basis quads: qslot = 4h+k at idx = qslot*128 + run*32 + row
  uint4* dq = buf + run * 32 + row;
#pragma unroll
  for (int k = 0; k < 4; ++k) {
    int j = (int)t8v[k]; j = j > 7 ? 7 : j;          // t8 in [0,8]
    unsigned int d[4];
    gen_basis(j, d);
    uint4 qv; qv.x = d[0]; qv.y = d[1]; qv.z = d[2]; qv.w = d[3];
    dq[(4 * h + k) * 128] = qv;
  }
  // x-octet (qslot 8): this half's 2 packed dwords (features 4h..4h+4)
  uint2 hv;
  hv.x = f2bf(xv[0]) | (f2bf(xv[1]) << 16);
  hv.y = f2bf(xv[2]) | (f2bf(xv[3]) << 16);
  ((uint2*)(buf + 8 * 128 + run * 32 + row))[h] = hv;
}

// ---------------------------------------------------------------------------
// K1: W into 32x32x16 B-fragment order under the aligned run layout.
// Fragment (c,s,u,nq) at Bsw[((c*9+s)*4 + 2u + nq)*64 + l]: lane l holds
// col o = 32nq+(l&31), k = qslot s of run R = 4c+2u+(l>>5). Short jj:
// s<8 -> (f=8R+s, n=jj); s==8 -> (f=8R+jj, n=8 i.e. base_weight).
// (Unchanged; verified rounds 6-10.)
// ---------------------------------------------------------------------------
__global__ __launch_bounds__(256) void build_w(const float* __restrict__ coeffs,
                                               const float* __restrict__ bw,
                                               uint4* __restrict__ Wsw) {
  const int l = threadIdx.x & 63;
  const int t = threadIdx.x >> 6;   // t = 2u+nq, 0..3
  const int g = blockIdx.x;         // 0..287
  const int c = g / 9, j = g - c * 9;
  const int u = t >> 1, nq = t & 1;
  const int R = c * 4 + 2 * u + (l >> 5);
  const int o = nq * 32 + (l & 31);
  unsigned int dwv[4];
#pragma unroll
  for (int jj = 0; jj < 8; ++jj) {
    int f, n;
    if (j < 8) { f = 8 * R + j;  n = jj; }
    else       { f = 8 * R + jj; n = 8;  }
    float v = (n < 8) ? coeffs[(f * 64 + o) * 8 + n] : bw[f * 64 + o];
    unsigned int hh = f2bf(v);
    if (jj & 1) dwv[jj >> 1] |= hh << 16; else dwv[jj >> 1] = hh;
  }
  uint4 qq; qq.x = dwv[0]; qq.y = dwv[1]; qq.z = dwv[2]; qq.w = dwv[3];
  Wsw[(g * 4 + t) * 64 + l] = qq;
}

#define MFMA32(A, B, C) __builtin_amdgcn_mfma_f32_32x32x16_bf16( \
    __builtin_bit_cast(short8, (A)), __builtin_bit_cast(short8, (B)), (C), 0, 0, 0)

// ---------------------------------------------------------------------------
// Main loop (R5-verified ordering): B loads -> build(next chunk) -> MFMA
// (current chunk from LDS) -> barrier. Wave ks: steps {ks+4i}, 32 rows x
// 64 cols; per step 2 contiguous ds_read_b128 (u=0,1) + 4 MFMAs.
// ---------------------------------------------------------------------------
template <int NS>
__device__ __forceinline__ void run_main(const float* __restrict__ xrow,
                                         const uint4* __restrict__ Bsw,
                                         uint4* __restrict__ Albuf,
                                         f32x16& acc0, f32x16& acc1,
                                         int ks, int l, int run, int row_b, int h) {
  const int hi = l >> 5;
  const int l31 = l & 31;
  float4 xa = *(const float4*)(xrow);
  build_half(xa, Albuf, run, row_b, h);        // chunk 0 -> buf0
  xa = *(const float4*)(xrow + 32);            // x for chunk 1
  BARRIER();

  for (int c = 0; c < 32; ++c) {
    uint4* cur = Albuf + (c & 1) * 1152;
    uint4* nxt = Albuf + ((c + 1) & 1) * 1152;
    // ---- B fragments for this chunk's NS steps (L2-hot) -------------------
    uint4 Bv[NS][4];
#pragma unroll
    for (int i = 0; i < NS; ++i) {
      const uint4* wp = Bsw + ((size_t)((c * 9 + ks + 4 * i) * 4)) * 64 + l;
      Bv[i][0] = wp[0]; Bv[i][1] = wp[64]; Bv[i][2] = wp[128]; Bv[i][3] = wp[192];
    }
    // ---- builder for chunk c+1 into the other buffer ----------------------
    if (c + 1 < 32) {
      build_half(xa, nxt, run, row_b, h);
      if (c + 2 < 32) xa = *(const float4*)(xrow + (c + 2) * 32);
    }
    // ---- MFMA: this wave's NS steps of chunk c ----------------------------
    __builtin_amdgcn_s_setprio(1);
#pragma unroll
    for (int i = 0; i < NS; ++i) {
      const int s = ks + 4 * i;
      const uint4* rb = cur + s * 128;
      uint4 a0 = rb[hi * 32 + l31];        // u=0: run hi
      uint4 a1 = rb[(2 + hi) * 32 + l31];  // u=1: run 2+hi
      acc0 = MFMA32(a0, Bv[i][0], acc0);   // u0, nq0
      acc1 = MFMA32(a0, Bv[i][1], acc1);   // u0, nq1
      acc0 = MFMA32(a1, Bv[i][2], acc0);   // u1, nq0
      acc1 = MFMA32(a1, Bv[i][3], acc1);   // u1, nq1
    }
    __builtin_amdgcn_s_setprio(0);
    BARRIER();   // writes to nxt visible; reads of cur drained
  }
}

// ---------------------------------------------------------------------------
// K2: 1024 blocks x 256 thr. Block = 32 rows x 64 cols; 4 blocks/CU (36KB
// LDS) at staggered phases. Wave w = ks (K-step quarter) = builder run.
// Builder lane: row = l>>1, half = l&1.
// ---------------------------------------------------------------------------
__global__ __launch_bounds__(256, 4) void wavelet_gemm(const float* __restrict__ x,
                                                       const uint4* __restrict__ Bsw,
                                                       float* __restrict__ out,
                                                       int out_size) {
  __shared__ uint4 Albuf[2 * 1152];   // 36 KB (reused as P[4][32][64] = 32 KB)
  const int tid = threadIdx.x;
  const int l = tid & 63;
  const int w = tid >> 6;            // wave 0..3
  const int ks = w;                  // K-step quarter (steps ks, ks+4[, 8])
  const int run = w;                 // builder run
  const int row_b = l >> 1;          // builder row 0..31
  const int h = l & 1;               // builder half-run
  const long rowbase = (long)blockIdx.x * 32;

  f32x16 acc0 = {};                  // cols 0..31
  f32x16 acc1 = {};                  // cols 32..63

  const float* xrow = x + (rowbase + row_b) * 1024 + run * 8 + h * 4;

  if (w == 0) run_main<3>(xrow, Bsw, Albuf, acc0, acc1, 0,  l, run, row_b, h);
  else        run_main<2>(xrow, Bsw, Albuf, acc0, acc1, ks, l, run, row_b, h);

  // ---- ks-partial store: P[ks][row 0..31][col 0..63]; 32x32 C/D layout
  // (verified): col = lane&31, row = (reg&3) + 8*(reg>>2) + 4*(lane>>5).
  float* P = (float*)Albuf;
  float* Pk = P + ks * 2048;
  const int l31 = l & 31;
  const int rbase = 4 * (l >> 5);
#pragma unroll
  for (int rg = 0; rg < 16; ++rg) {
    const int grow = (rg & 3) + 8 * (rg >> 2) + rbase;
    Pk[grow * 64 + l31]      = acc0[rg];
    Pk[grow * 64 + 32 + l31] = acc1[rg];
  }
  BARRIER();

  // ---- reduce 4 ks-partials; coalesced store (8 floats/thread) -----------
  float* og = out + (size_t)rowbase * 64;
  const int d = tid * 8;
  f32x4 v0 = *(const f32x4*)(P + d)     + *(const f32x4*)(P + 2048 + d)
           + *(const f32x4*)(P + 4096 + d) + *(const f32x4*)(P + 6144 + d);
  f32x4 v1 = *(const f32x4*)(P + d + 4) + *(const f32x4*)(P + 2048 + d + 4)
           + *(const f32x4*)(P + 4096 + d + 4) + *(const f32x4*)(P + 6144 + d + 4);
  *(f32x4*)(og + d) = v0;
  *(f32x4*)(og + d + 4) = v1;
  if (blockIdx.x == 0 && tid == 0) out[out_size - 1] = 0.0f;  // kl = 0
}

extern "C" void kernel_launch(void* const* d_in, const int* in_sizes, int n_in,
                              void* d_out, int out_size, void* d_ws, size_t ws_size,
                              hipStream_t stream) {
  const float* x      = (const float*)d_in[0];   // [32768,1024] f32
  const float* coeffs = (const float*)d_in[1];   // [1024,64,8] f32
  const float* bw     = (const float*)d_in[2];   // [1024,64] f32
  uint4* Wsw = (uint4*)d_ws;                     // 288*4*64*16 = 1.125 MiB
  float* out = (float*)d_out;

  build_w<<<288, 256, 0, stream>>>(coeffs, bw, Wsw);
  wavelet_gemm<<<1024, 256, 0, stream>>>(x, (const uint4*)Wsw, out, out_size);
}